// Round 2
// baseline (994.302 us; speedup 1.0000x reference)
//
#include <hip/hip_runtime.h>
#include <math.h>

#define HW 16384

// ---------------- K0: merge the three 3x3 weight arrays into Wcat[603][64][9] + Bcat ----
__global__ __launch_bounds__(256) void k_merge(
    const float* __restrict__ wp, const float* __restrict__ bp,
    const float* __restrict__ wm, const float* __restrict__ bm,
    const float* __restrict__ wc, const float* __restrict__ bc,
    float* __restrict__ Wcat, float* __restrict__ Bcat) {
  int i = blockIdx.x * 256 + threadIdx.x;
  const int total = 603 * 576;
  if (i < total) {
    int g = i / 576, r = i - g * 576;
    float v;
    if (g < 18)      v = wp[g * 576 + r];
    else if (g < 27) v = wm[(g - 18) * 576 + r];
    else             v = wc[(g - 27) * 576 + r];
    Wcat[i] = v;
  }
  if (i < 603) {
    Bcat[i] = (i < 18) ? bp[i] : (i < 27) ? bm[i - 18] : bc[i - 27];
  }
}

// ---------------- K1: fused = 1x1 conv over concat(x, ref) (128 -> 64 ch) --------------
__global__ __launch_bounds__(256) void k_fused(
    const float* __restrict__ x, const float* __restrict__ ref,
    const float* __restrict__ wcd, const float* __restrict__ bcd,
    float* __restrict__ fused) {
  __shared__ float sw[128 * 64];  // transposed: [ci][o]
  __shared__ float sb[64];
  for (int i = threadIdx.x; i < 128 * 64; i += 256) {
    int ci = i >> 6, o = i & 63;
    sw[i] = wcd[o * 128 + ci];
  }
  if (threadIdx.x < 64) sb[threadIdx.x] = bcd[threadIdx.x];
  __syncthreads();

  int pix = blockIdx.x * 256 + threadIdx.x;   // 0..65535
  int b = pix >> 14, hw = pix & 16383;
  const float* xb = x   + ((size_t)b * 64 << 14) + hw;
  const float* rb = ref + ((size_t)b * 64 << 14) + hw;

  float4 acc[16];
  #pragma unroll
  for (int o4 = 0; o4 < 16; o4++)
    acc[o4] = make_float4(sb[4*o4], sb[4*o4+1], sb[4*o4+2], sb[4*o4+3]);

  for (int ci = 0; ci < 64; ci++) {
    float v = xb[(size_t)ci << 14];
    const float4* wr = (const float4*)&sw[ci * 64];
    #pragma unroll
    for (int o4 = 0; o4 < 16; o4++) {
      float4 w4 = wr[o4];
      acc[o4].x += w4.x * v; acc[o4].y += w4.y * v;
      acc[o4].z += w4.z * v; acc[o4].w += w4.w * v;
    }
  }
  for (int ci = 0; ci < 64; ci++) {
    float v = rb[(size_t)ci << 14];
    const float4* wr = (const float4*)&sw[(64 + ci) * 64];
    #pragma unroll
    for (int o4 = 0; o4 < 16; o4++) {
      float4 w4 = wr[o4];
      acc[o4].x += w4.x * v; acc[o4].y += w4.y * v;
      acc[o4].z += w4.z * v; acc[o4].w += w4.w * v;
    }
  }
  float* fb = fused + ((size_t)b * 64 << 14) + hw;
  #pragma unroll
  for (int o4 = 0; o4 < 16; o4++) {
    fb[(size_t)(4*o4+0) << 14] = acc[o4].x;
    fb[(size_t)(4*o4+1) << 14] = acc[o4].y;
    fb[(size_t)(4*o4+2) << 14] = acc[o4].z;
    fb[(size_t)(4*o4+3) << 14] = acc[o4].w;
  }
}

// ---------------- K2: 3x3 conv pad=1, 64 ch -> 603 ch, with per-head activation --------
// head channels: [0..18) off (linear), [18..27) mod (sigmoid), [27..603) col (tanh)
// block: 16x16 pixel tile x 64 oc; thread: 8 contiguous cols x 8 oc register tile.
__global__ __launch_bounds__(256) void k_conv3x3(
    const float* __restrict__ fused, const float* __restrict__ Wcat,
    const float* __restrict__ Bcat, float* __restrict__ head) {
  __shared__ float sin_[8 * 360];       // [ci][18 rows][stride 20]
  __shared__ float swt[8 * 9 * 64];     // [cil][k][oc]
  const int t = threadIdx.x;
  const int w0 = blockIdx.x * 16, h0 = blockIdx.y * 16;
  const int b = blockIdx.z / 10, og = blockIdx.z % 10;
  const int ocg = t >> 5;         // 0..7  (8 oc each)
  const int rem = t & 31;
  const int r   = rem >> 1;       // 0..15 pixel row
  const int cg  = rem & 1;        // 0..1  (8-col group)

  float acc[8][8];
  #pragma unroll
  for (int p = 0; p < 8; p++)
    #pragma unroll
    for (int o = 0; o < 8; o++) acc[p][o] = 0.f;

  for (int ci0 = 0; ci0 < 64; ci0 += 8) {
    __syncthreads();
    // stage input 8 ci x 18x18 halo (zero-padded at image borders)
    for (int i = t; i < 8 * 360; i += 256) {
      int ci = i / 360, rm = i - ci * 360, rr = rm / 20, cc = rm - rr * 20;
      if (cc < 18) {
        int gh = h0 - 1 + rr, gw = w0 - 1 + cc;
        float v = 0.f;
        if (gh >= 0 && gh < 128 && gw >= 0 && gw < 128)
          v = fused[(((size_t)b * 64 + ci0 + ci) << 14) + (gh << 7) + gw];
        sin_[i] = v;
      }
    }
    // stage weights [cil][k][oc 0..63]
    for (int i = t; i < 8 * 9 * 64; i += 256) {
      int oc = i & 63, rest = i >> 6;
      int k = rest % 9, cil = rest / 9;
      int g = og * 64 + oc;
      swt[i] = (g < 603) ? Wcat[(size_t)g * 576 + (ci0 + cil) * 9 + k] : 0.f;
    }
    __syncthreads();

    #pragma unroll
    for (int cil = 0; cil < 8; cil++) {
      float in[3][10];
      #pragma unroll
      for (int dr = 0; dr < 3; dr++) {
        const float* rowp = &sin_[cil * 360 + (r + dr) * 20 + cg * 8];
        float4 a  = *(const float4*)rowp;
        float4 bb = *(const float4*)(rowp + 4);
        float2 c2 = *(const float2*)(rowp + 8);
        in[dr][0]=a.x;  in[dr][1]=a.y;  in[dr][2]=a.z;  in[dr][3]=a.w;
        in[dr][4]=bb.x; in[dr][5]=bb.y; in[dr][6]=bb.z; in[dr][7]=bb.w;
        in[dr][8]=c2.x; in[dr][9]=c2.y;
      }
      #pragma unroll
      for (int k = 0; k < 9; k++) {
        const int dr = k / 3, dc = k % 3;
        const float4* wp4 = (const float4*)&swt[(cil * 9 + k) * 64 + ocg * 8];
        float4 wa = wp4[0], wb = wp4[1];
        float wv[8] = {wa.x, wa.y, wa.z, wa.w, wb.x, wb.y, wb.z, wb.w};
        #pragma unroll
        for (int p = 0; p < 8; p++) {
          float iv = in[dr][p + dc];
          #pragma unroll
          for (int o = 0; o < 8; o++) acc[p][o] += iv * wv[o];
        }
      }
    }
  }

  // store with bias + activation
  const int gw0 = w0 + cg * 8;
  const int gh  = h0 + r;
  #pragma unroll
  for (int o = 0; o < 8; o++) {
    int g = og * 64 + ocg * 8 + o;
    if (g < 603) {
      float bias = Bcat[g];
      float vals[8];
      #pragma unroll
      for (int p = 0; p < 8; p++) {
        float v = acc[p][o] + bias;
        if (g >= 27)      v = tanhf(v);
        else if (g >= 18) v = 1.f / (1.f + expf(-v));
        vals[p] = v;
      }
      float* hp = head + (((size_t)b * 603 + g) << 14) + (gh << 7) + gw0;
      *(float4*)hp       = make_float4(vals[0], vals[1], vals[2], vals[3]);
      *(float4*)(hp + 4) = make_float4(vals[4], vals[5], vals[6], vals[7]);
    }
  }
}

// ---------------- K3: bilinear sample + color + modulation + 64x576 contraction --------
__global__ __launch_bounds__(256) void k_sample(
    const float* __restrict__ x, const float* __restrict__ head,
    const float* __restrict__ wconv, float* __restrict__ out) {
  __shared__ float swc[8 * 9 * 64];   // [cl][k][o]
  const int t = threadIdx.x;
  const int pix = blockIdx.x * 256 + t;
  const int b = pix >> 14, hw = pix & 16383;
  const int h = hw >> 7, w = hw & 127;

  const float* hb = head + (((size_t)b * 603) << 14) + hw;

  float wl[9][4];
  int   ofs[9][4];
  float mk[9];
  #pragma unroll
  for (int k = 0; k < 9; k++) {
    float ox = hb[(size_t)k << 14];
    float oy = hb[(size_t)(9 + k) << 14];
    mk[k]    = hb[(size_t)(18 + k) << 14];
    // px = (h+1) + off_x + (k/3 - 1); py = (w+1) + off_y + (k%3 - 1)
    float px = (float)(h + k / 3) + ox;
    float py = (float)(w + k % 3) + oy;
    float fx = floorf(px), fy = floorf(py);
    float qltx = fminf(fmaxf(fx, 0.f), 129.f);
    float qlty = fminf(fmaxf(fy, 0.f), 129.f);
    float qrbx = fminf(fmaxf(fx + 1.f, 0.f), 129.f);
    float qrby = fminf(fmaxf(fy + 1.f, 0.f), 129.f);
    float sx = fminf(fmaxf(px, 0.f), 129.f);
    float sy = fminf(fmaxf(py, 0.f), 129.f);
    float ax = 1.f + qltx - sx, bx = 1.f - qrbx + sx;
    float ay = 1.f + qlty - sy, by = 1.f - qrby + sy;
    int iltx = (int)qltx, ilty = (int)qlty, irbx = (int)qrbx, irby = (int)qrby;
    bool vltx = (iltx >= 1) && (iltx <= 128);
    bool vlty = (ilty >= 1) && (ilty <= 128);
    bool vrbx = (irbx >= 1) && (irbx <= 128);
    bool vrby = (irby >= 1) && (irby <= 128);
    // padded value is 0 outside [1,128]^2 -> zero the weight instead of the load
    wl[k][0] = (vltx && vlty) ? ax * ay : 0.f;
    wl[k][1] = (vrbx && vrby) ? bx * by : 0.f;
    wl[k][2] = (vltx && vrby) ? ax * by : 0.f;
    wl[k][3] = (vrbx && vlty) ? bx * ay : 0.f;
    ofs[k][0] = (vltx && vlty) ? ((iltx - 1) << 7) + (ilty - 1) : 0;
    ofs[k][1] = (vrbx && vrby) ? ((irbx - 1) << 7) + (irby - 1) : 0;
    ofs[k][2] = (vltx && vrby) ? ((iltx - 1) << 7) + (irby - 1) : 0;
    ofs[k][3] = (vrbx && vlty) ? ((irbx - 1) << 7) + (ilty - 1) : 0;
  }

  float4 acc[16];
  #pragma unroll
  for (int i = 0; i < 16; i++) acc[i] = make_float4(0.f, 0.f, 0.f, 0.f);

  const float* colb = hb + ((size_t)27 << 14);
  for (int c0 = 0; c0 < 64; c0 += 8) {
    __syncthreads();
    for (int i = t; i < 8 * 9 * 64; i += 256) {
      int o = i & 63, rest = i >> 6;
      int k = rest % 9, cl = rest / 9;
      swc[i] = wconv[(size_t)o * 576 + (c0 + cl) * 9 + k];
    }
    __syncthreads();
    #pragma unroll
    for (int cl = 0; cl < 8; cl++) {
      int c = c0 + cl;
      const float* xc = x + (((size_t)b * 64 + c) << 14);
      const float* cp = colb + ((size_t)(c * 9) << 14);
      float inp[9];
      #pragma unroll
      for (int k = 0; k < 9; k++) {
        float pos = wl[k][0] * xc[ofs[k][0]] + wl[k][1] * xc[ofs[k][1]]
                  + wl[k][2] * xc[ofs[k][2]] + wl[k][3] * xc[ofs[k][3]];
        inp[k] = (cp[(size_t)k << 14] + pos) * mk[k];
      }
      #pragma unroll
      for (int k = 0; k < 9; k++) {
        const float4* wr = (const float4*)&swc[(cl * 9 + k) * 64];
        float v = inp[k];
        #pragma unroll
        for (int o4 = 0; o4 < 16; o4++) {
          float4 w4 = wr[o4];
          acc[o4].x += w4.x * v; acc[o4].y += w4.y * v;
          acc[o4].z += w4.z * v; acc[o4].w += w4.w * v;
        }
      }
    }
  }

  float* ob = out + (((size_t)b * 64) << 14) + hw;
  #pragma unroll
  for (int o4 = 0; o4 < 16; o4++) {
    ob[(size_t)(4*o4+0) << 14] = acc[o4].x;
    ob[(size_t)(4*o4+1) << 14] = acc[o4].y;
    ob[(size_t)(4*o4+2) << 14] = acc[o4].z;
    ob[(size_t)(4*o4+3) << 14] = acc[o4].w;
  }
}

extern "C" void kernel_launch(void* const* d_in, const int* in_sizes, int n_in,
                              void* d_out, int out_size, void* d_ws, size_t ws_size,
                              hipStream_t stream) {
  const float* x     = (const float*)d_in[0];
  const float* ref   = (const float*)d_in[1];
  const float* wcd   = (const float*)d_in[2];
  const float* bcd   = (const float*)d_in[3];
  const float* wp    = (const float*)d_in[4];
  const float* bp    = (const float*)d_in[5];
  const float* wm    = (const float*)d_in[6];
  const float* bm    = (const float*)d_in[7];
  const float* wc    = (const float*)d_in[8];
  const float* bc    = (const float*)d_in[9];
  const float* wconv = (const float*)d_in[10];
  float* out = (float*)d_out;

  float* ws    = (float*)d_ws;
  float* Wcat  = ws;                    // 603*576 = 347328 floats
  float* Bcat  = Wcat + 347328;         // 603 (padded to 704)
  float* fused = Bcat + 704;            // 4*64*16384 = 4194304 floats
  float* head  = fused + 4194304;       // 4*603*16384 = 39518208 floats
  // total ~176.3 MB of workspace

  k_merge  <<<1357, 256, 0, stream>>>(wp, bp, wm, bm, wc, bc, Wcat, Bcat);
  k_fused  <<<256, 256, 0, stream>>>(x, ref, wcd, bcd, fused);
  k_conv3x3<<<dim3(8, 8, 40), 256, 0, stream>>>(fused, Wcat, Bcat, head);
  k_sample <<<256, 256, 0, stream>>>(x, head, wconv, out);
}

// Round 3
// 531.289 us; speedup vs baseline: 1.8715x; 1.8715x over previous
//
#include <hip/hip_runtime.h>
#include <math.h>

typedef short s16x8 __attribute__((ext_vector_type(8)));
typedef float f32x4 __attribute__((ext_vector_type(4)));

__device__ inline ushort f2bf(float f) {
  unsigned u = __float_as_uint(f);
  u = (u + 0x7FFF + ((u >> 16) & 1)) >> 16;
  return (ushort)u;
}
__device__ inline float bf2f(ushort u) {
  return __uint_as_float(((unsigned)u) << 16);
}
__device__ inline void gload_lds16(const void* g, void* l) {
  __builtin_amdgcn_global_load_lds(
      (const __attribute__((address_space(1))) unsigned*)g,
      (__attribute__((address_space(3))) unsigned*)l, 16, 0, 0);
}

// ---------------- K0: weights -> Wb bf16 [640][576] (zero-pad >=603) + Bc fp32[640] ----
__global__ __launch_bounds__(256) void k_merge(
    const float* __restrict__ wp, const float* __restrict__ bp,
    const float* __restrict__ wm, const float* __restrict__ bm,
    const float* __restrict__ wc, const float* __restrict__ bc,
    ushort* __restrict__ Wb, float* __restrict__ Bc) {
  int i = blockIdx.x * 256 + threadIdx.x;
  if (i < 640 * 576) {
    int g = i / 576, r = i - g * 576;
    float v = 0.f;
    if (g < 18)       v = wp[g * 576 + r];
    else if (g < 27)  v = wm[(g - 18) * 576 + r];
    else if (g < 603) v = wc[(g - 27) * 576 + r];
    Wb[i] = f2bf(v);
  }
  if (i < 640)
    Bc[i] = (i < 18) ? bp[i] : (i < 27) ? bm[i - 18] : (i < 603) ? bc[i - 27] : 0.f;
}

// ---------------- K1: fused = 1x1 conv over concat(x, ref), output bf16 ----------------
__global__ __launch_bounds__(256) void k_fused(
    const float* __restrict__ x, const float* __restrict__ ref,
    const float* __restrict__ wcd, const float* __restrict__ bcd,
    ushort* __restrict__ fusedb) {
  __shared__ float sw[128 * 64];
  __shared__ float sb[64];
  for (int i = threadIdx.x; i < 128 * 64; i += 256) {
    int ci = i >> 6, o = i & 63;
    sw[i] = wcd[o * 128 + ci];
  }
  if (threadIdx.x < 64) sb[threadIdx.x] = bcd[threadIdx.x];
  __syncthreads();

  int pix = blockIdx.x * 256 + threadIdx.x;
  int b = pix >> 14, hw = pix & 16383;
  const float* xb = x   + ((size_t)b * 64 << 14) + hw;
  const float* rb = ref + ((size_t)b * 64 << 14) + hw;

  float4 acc[16];
  #pragma unroll
  for (int o4 = 0; o4 < 16; o4++)
    acc[o4] = make_float4(sb[4*o4], sb[4*o4+1], sb[4*o4+2], sb[4*o4+3]);

  for (int ci = 0; ci < 64; ci++) {
    float v = xb[(size_t)ci << 14];
    const float4* wr = (const float4*)&sw[ci * 64];
    #pragma unroll
    for (int o4 = 0; o4 < 16; o4++) {
      float4 w4 = wr[o4];
      acc[o4].x += w4.x * v; acc[o4].y += w4.y * v;
      acc[o4].z += w4.z * v; acc[o4].w += w4.w * v;
    }
  }
  for (int ci = 0; ci < 64; ci++) {
    float v = rb[(size_t)ci << 14];
    const float4* wr = (const float4*)&sw[(64 + ci) * 64];
    #pragma unroll
    for (int o4 = 0; o4 < 16; o4++) {
      float4 w4 = wr[o4];
      acc[o4].x += w4.x * v; acc[o4].y += w4.y * v;
      acc[o4].z += w4.z * v; acc[o4].w += w4.w * v;
    }
  }
  ushort* fb = fusedb + ((size_t)b * 64 << 14) + hw;
  #pragma unroll
  for (int o4 = 0; o4 < 16; o4++) {
    fb[(size_t)(4*o4+0) << 14] = f2bf(acc[o4].x);
    fb[(size_t)(4*o4+1) << 14] = f2bf(acc[o4].y);
    fb[(size_t)(4*o4+2) << 14] = f2bf(acc[o4].z);
    fb[(size_t)(4*o4+3) << 14] = f2bf(acc[o4].w);
  }
}

// ---------------- K2a: im2col A[m=65536][k=576] bf16 (k = ci*9 + kk) -------------------
__global__ __launch_bounds__(256) void k_im2col(
    const ushort* __restrict__ fusedb, ushort* __restrict__ A) {
  __shared__ ushort sF[64 * 432];   // [ci][dr 3][144], row data at col offset 8
  const int t = threadIdx.x;
  const int bh = blockIdx.x;        // (b,h): b = bh>>7, h = bh&127
  const int b = bh >> 7, h = bh & 127;

  for (int idx = t; idx < 3072; idx += 256) {       // 64ci x 3dr x 16 w8-chunks
    int ci = idx / 48, rem = idx - ci * 48, dr = rem >> 4, w8 = rem & 15;
    int gh = h + dr - 1;
    uint4 v = make_uint4(0u, 0u, 0u, 0u);
    if (gh >= 0 && gh < 128)
      v = *(const uint4*)(fusedb + (((size_t)(b * 64 + ci)) << 14) + (gh << 7) + w8 * 8);
    *(uint4*)(&sF[ci * 432 + dr * 144 + 8 + w8 * 8]) = v;
  }
  for (int idx = t; idx < 192; idx += 256) {        // zero halo cols 7 and 136
    int ci = idx / 3, dr = idx - ci * 3;
    sF[ci * 432 + dr * 144 + 7]   = 0;
    sF[ci * 432 + dr * 144 + 136] = 0;
  }
  __syncthreads();

  const size_t mbase = (size_t)bh * 128;
  #pragma unroll 1
  for (int it = 0; it < 36; it++) {
    int idx = it * 256 + t;                 // 0..9215 = 128 w x 72 kgroups
    int kg8 = idx & 7, w8i = (idx >> 3) & 7;
    int rest = idx >> 6;
    int kghi = rest % 9, whi = rest / 9;
    int kg = kghi * 8 + kg8;                // 0..71
    int w  = whi * 8 + w8i;                 // 0..127
    ushort vals[8];
    #pragma unroll
    for (int j = 0; j < 8; j++) {
      int kgl = kg * 8 + j;
      int ci = kgl / 9, kk = kgl - ci * 9;
      int dr = kk / 3, dc = kk - dr * 3;
      vals[j] = sF[ci * 432 + dr * 144 + w + dc + 7];
    }
    *(uint4*)(A + (mbase + w) * 576 + kg * 8) = *(uint4*)vals;
  }
}

// ---------------- K2b: MFMA GEMM D[oc 640][pix] = Wb x A^T, fused bias+act -------------
// grid: (og 10, ptile 256); block 256 = 4 waves; tile 64 oc x 256 pix; K=576, BK=32.
__global__ __launch_bounds__(256) void k_gemm(
    const ushort* __restrict__ Wb, const ushort* __restrict__ A,
    const float* __restrict__ Bc,
    float* __restrict__ headom, ushort* __restrict__ headcol) {
  __shared__ __align__(16) ushort sW[64 * 32];    // [oc row][k slot-swizzled]
  __shared__ __align__(16) ushort sP[256 * 32];   // [pix row][k slot-swizzled]
  const int t = threadIdx.x;
  const int lane = t & 63, wv = t >> 6;
  const int og = blockIdx.x;              // 0..9
  const int m0 = blockIdx.y * 256;        // pixel base; whole block in one b
  const int bb = m0 >> 14, hw0 = m0 & 16383;

  const ushort* Wrow = Wb + (size_t)(og * 64) * 576;

  f32x4 acc[4][4];
  #pragma unroll
  for (int mi = 0; mi < 4; mi++)
    #pragma unroll
    for (int ni = 0; ni < 4; ni++) acc[mi][ni] = (f32x4){0.f, 0.f, 0.f, 0.f};

  const int srow = lane >> 2, sslot = lane & 3;

  for (int ks = 0; ks < 18; ks++) {
    const int k0 = ks * 32;
    __syncthreads();
    { // stage W tile: wave w covers rows [w*16, w*16+16)
      int row = (wv << 4) + srow;
      int g = (sslot - (row >> 1)) & 3;
      gload_lds16(Wrow + (size_t)row * 576 + k0 + g * 8, sW + (wv << 9));
    }
    #pragma unroll
    for (int c = 0; c < 4; c++) { // stage P tile: wave w covers rows [w*64, w*64+64)
      int prow = (wv << 6) + (c << 4) + srow;
      int g = (sslot - (prow >> 1)) & 3;
      gload_lds16(A + (size_t)(m0 + prow) * 576 + k0 + g * 8,
                  sP + (((wv << 6) + (c << 4)) << 5));
    }
    __syncthreads();

    const int nif = lane & 15, kb = lane >> 4;
    s16x8 af[4], bf[4];
    #pragma unroll
    for (int mi = 0; mi < 4; mi++) {
      int m = mi * 16 + nif;
      int s = (kb + (m >> 1)) & 3;
      af[mi] = *(const s16x8*)(sW + m * 32 + s * 8);
    }
    #pragma unroll
    for (int ni = 0; ni < 4; ni++) {
      int r = (wv << 6) + ni * 16 + nif;
      int s = (kb + (r >> 1)) & 3;
      bf[ni] = *(const s16x8*)(sP + r * 32 + s * 8);
    }
    #pragma unroll
    for (int mi = 0; mi < 4; mi++)
      #pragma unroll
      for (int ni = 0; ni < 4; ni++)
        acc[mi][ni] = __builtin_amdgcn_mfma_f32_16x16x32_bf16(af[mi], bf[ni], acc[mi][ni], 0, 0, 0);
  }

  // epilogue: D row m -> oc g = og*64+m (activation per head), col n -> pixel
  const int nif = lane & 15, quad = lane >> 4;
  #pragma unroll
  for (int mi = 0; mi < 4; mi++) {
    #pragma unroll
    for (int ni = 0; ni < 4; ni++) {
      int pixl = (wv << 6) + ni * 16 + nif;
      int hw = hw0 + pixl;
      #pragma unroll
      for (int r = 0; r < 4; r++) {
        int g = og * 64 + mi * 16 + quad * 4 + r;
        float v = acc[mi][ni][r] + Bc[g];
        if (g < 18) {
          headom[(((size_t)bb * 27 + g) << 14) + hw] = v;
        } else if (g < 27) {
          headom[(((size_t)bb * 27 + g) << 14) + hw] = 1.f / (1.f + expf(-v));
        } else if (g < 603) {
          headcol[(((size_t)bb * 576 + (g - 27)) << 14) + hw] = f2bf(tanhf(v));
        }
      }
    }
  }
}

// ---------------- K3: bilinear sample + color + modulation + 64x576 contraction --------
__global__ __launch_bounds__(256) void k_sample(
    const float* __restrict__ x, const float* __restrict__ headom,
    const ushort* __restrict__ headcol,
    const float* __restrict__ wconv, float* __restrict__ out) {
  __shared__ float swc[8 * 9 * 64];   // [cl][k][o]
  const int t = threadIdx.x;
  const int pix = blockIdx.x * 256 + t;
  const int b = pix >> 14, hw = pix & 16383;
  const int h = hw >> 7, w = hw & 127;

  const float* hbom = headom + (((size_t)b * 27) << 14) + hw;

  float wl[9][4];
  int   ofs[9][4];
  float mk[9];
  #pragma unroll
  for (int k = 0; k < 9; k++) {
    float ox = hbom[(size_t)k << 14];
    float oy = hbom[(size_t)(9 + k) << 14];
    mk[k]    = hbom[(size_t)(18 + k) << 14];
    float px = (float)(h + k / 3) + ox;
    float py = (float)(w + k % 3) + oy;
    float fx = floorf(px), fy = floorf(py);
    float qltx = fminf(fmaxf(fx, 0.f), 129.f);
    float qlty = fminf(fmaxf(fy, 0.f), 129.f);
    float qrbx = fminf(fmaxf(fx + 1.f, 0.f), 129.f);
    float qrby = fminf(fmaxf(fy + 1.f, 0.f), 129.f);
    float sx = fminf(fmaxf(px, 0.f), 129.f);
    float sy = fminf(fmaxf(py, 0.f), 129.f);
    float ax = 1.f + qltx - sx, bx = 1.f - qrbx + sx;
    float ay = 1.f + qlty - sy, by = 1.f - qrby + sy;
    int iltx = (int)qltx, ilty = (int)qlty, irbx = (int)qrbx, irby = (int)qrby;
    bool vltx = (iltx >= 1) && (iltx <= 128);
    bool vlty = (ilty >= 1) && (ilty <= 128);
    bool vrbx = (irbx >= 1) && (irbx <= 128);
    bool vrby = (irby >= 1) && (irby <= 128);
    wl[k][0] = (vltx && vlty) ? ax * ay : 0.f;
    wl[k][1] = (vrbx && vrby) ? bx * by : 0.f;
    wl[k][2] = (vltx && vrby) ? ax * by : 0.f;
    wl[k][3] = (vrbx && vlty) ? bx * ay : 0.f;
    ofs[k][0] = (vltx && vlty) ? ((iltx - 1) << 7) + (ilty - 1) : 0;
    ofs[k][1] = (vrbx && vrby) ? ((irbx - 1) << 7) + (irby - 1) : 0;
    ofs[k][2] = (vltx && vrby) ? ((iltx - 1) << 7) + (irby - 1) : 0;
    ofs[k][3] = (vrbx && vlty) ? ((irbx - 1) << 7) + (ilty - 1) : 0;
  }

  float4 acc[16];
  #pragma unroll
  for (int i = 0; i < 16; i++) acc[i] = make_float4(0.f, 0.f, 0.f, 0.f);

  const ushort* colb = headcol + (((size_t)b * 576) << 14) + hw;
  for (int c0 = 0; c0 < 64; c0 += 8) {
    __syncthreads();
    for (int i = t; i < 8 * 9 * 64; i += 256) {
      int o = i & 63, rest = i >> 6;
      int k = rest % 9, cl = rest / 9;
      swc[i] = wconv[(size_t)o * 576 + (c0 + cl) * 9 + k];
    }
    __syncthreads();
    #pragma unroll
    for (int cl = 0; cl < 8; cl++) {
      int c = c0 + cl;
      const float* xc = x + (((size_t)b * 64 + c) << 14);
      const ushort* cp = colb + ((size_t)(c * 9) << 14);
      float inp[9];
      #pragma unroll
      for (int k = 0; k < 9; k++) {
        float pos = wl[k][0] * xc[ofs[k][0]] + wl[k][1] * xc[ofs[k][1]]
                  + wl[k][2] * xc[ofs[k][2]] + wl[k][3] * xc[ofs[k][3]];
        inp[k] = (bf2f(cp[(size_t)k << 14]) + pos) * mk[k];
      }
      #pragma unroll
      for (int k = 0; k < 9; k++) {
        const float4* wr = (const float4*)&swc[(cl * 9 + k) * 64];
        float v = inp[k];
        #pragma unroll
        for (int o4 = 0; o4 < 16; o4++) {
          float4 w4 = wr[o4];
          acc[o4].x += w4.x * v; acc[o4].y += w4.y * v;
          acc[o4].z += w4.z * v; acc[o4].w += w4.w * v;
        }
      }
    }
  }

  float* ob = out + (((size_t)b * 64) << 14) + hw;
  #pragma unroll
  for (int o4 = 0; o4 < 16; o4++) {
    ob[(size_t)(4*o4+0) << 14] = acc[o4].x;
    ob[(size_t)(4*o4+1) << 14] = acc[o4].y;
    ob[(size_t)(4*o4+2) << 14] = acc[o4].z;
    ob[(size_t)(4*o4+3) << 14] = acc[o4].w;
  }
}

extern "C" void kernel_launch(void* const* d_in, const int* in_sizes, int n_in,
                              void* d_out, int out_size, void* d_ws, size_t ws_size,
                              hipStream_t stream) {
  const float* x     = (const float*)d_in[0];
  const float* ref   = (const float*)d_in[1];
  const float* wcd   = (const float*)d_in[2];
  const float* bcd   = (const float*)d_in[3];
  const float* wp    = (const float*)d_in[4];
  const float* bp    = (const float*)d_in[5];
  const float* wm    = (const float*)d_in[6];
  const float* bm    = (const float*)d_in[7];
  const float* wc    = (const float*)d_in[8];
  const float* bc    = (const float*)d_in[9];
  const float* wconv = (const float*)d_in[10];
  float* out = (float*)d_out;

  char* w8 = (char*)d_ws;
  ushort* Wb      = (ushort*)(w8 + 0);          //   737,280 B
  float*  Bc      = (float*)(w8 + 737280);      //     2,560 B
  ushort* fusedb  = (ushort*)(w8 + 739840);     // 8,388,608 B
  ushort* A       = (ushort*)(w8 + 9128448);    // 75,497,472 B
  float*  headom  = (float*)(w8 + 84625920);    //  7,077,888 B
  ushort* headcol = (ushort*)(w8 + 91703808);   // 75,497,472 B -> end 167,201,280 B

  k_merge <<<1440, 256, 0, stream>>>(wp, bp, wm, bm, wc, bc, Wb, Bc);
  k_fused <<<256, 256, 0, stream>>>(x, ref, wcd, bcd, fusedb);
  k_im2col<<<512, 256, 0, stream>>>(fusedb, A);
  k_gemm  <<<dim3(10, 256), 256, 0, stream>>>(Wb, A, Bc, headom, headcol);
  k_sample<<<256, 256, 0, stream>>>(x, headom, headcol, wconv, out);
}

// Round 4
// 457.689 us; speedup vs baseline: 2.1724x; 1.1608x over previous
//
#include <hip/hip_runtime.h>
#include <math.h>

typedef short s16x8 __attribute__((ext_vector_type(8)));
typedef float f32x4 __attribute__((ext_vector_type(4)));

__device__ inline ushort f2bf(float f) {
  unsigned u = __float_as_uint(f);
  u = (u + 0x7FFF + ((u >> 16) & 1)) >> 16;
  return (ushort)u;
}
__device__ inline float bf2f(ushort u) {
  return __uint_as_float(((unsigned)u) << 16);
}
__device__ inline void gload_lds16(const void* g, void* l) {
  __builtin_amdgcn_global_load_lds(
      (const __attribute__((address_space(1))) unsigned*)g,
      (__attribute__((address_space(3))) unsigned*)l, 16, 0, 0);
}

// ---- K0: Wb bf16[640][576] (head weights, zero-pad >=603) + Bc[640] + Wb2 bf16[64][576]
__global__ __launch_bounds__(256) void k_merge(
    const float* __restrict__ wp, const float* __restrict__ bp,
    const float* __restrict__ wm, const float* __restrict__ bm,
    const float* __restrict__ wc, const float* __restrict__ bc,
    const float* __restrict__ wconv,
    ushort* __restrict__ Wb, float* __restrict__ Bc, ushort* __restrict__ Wb2) {
  int i = blockIdx.x * 256 + threadIdx.x;
  if (i < 640 * 576) {
    int g = i / 576, r = i - g * 576;
    float v = 0.f;
    if (g < 18)       v = wp[g * 576 + r];
    else if (g < 27)  v = wm[(g - 18) * 576 + r];
    else if (g < 603) v = wc[(g - 27) * 576 + r];
    Wb[i] = f2bf(v);
  }
  if (i < 64 * 576) Wb2[i] = f2bf(wconv[i]);
  if (i < 640)
    Bc[i] = (i < 18) ? bp[i] : (i < 27) ? bm[i - 18] : (i < 603) ? bc[i - 27] : 0.f;
}

// ---- K1: fused = 1x1 conv over concat(x, ref), output bf16 [64][B*HW] -----------------
__global__ __launch_bounds__(256) void k_fused(
    const float* __restrict__ x, const float* __restrict__ ref,
    const float* __restrict__ wcd, const float* __restrict__ bcd,
    ushort* __restrict__ fusedb) {
  __shared__ float sw[128 * 64];
  __shared__ float sb[64];
  for (int i = threadIdx.x; i < 128 * 64; i += 256) {
    int ci = i >> 6, o = i & 63;
    sw[i] = wcd[o * 128 + ci];
  }
  if (threadIdx.x < 64) sb[threadIdx.x] = bcd[threadIdx.x];
  __syncthreads();

  int pix = blockIdx.x * 256 + threadIdx.x;
  int b = pix >> 14, hw = pix & 16383;
  const float* xb = x   + ((size_t)b * 64 << 14) + hw;
  const float* rb = ref + ((size_t)b * 64 << 14) + hw;

  float4 acc[16];
  #pragma unroll
  for (int o4 = 0; o4 < 16; o4++)
    acc[o4] = make_float4(sb[4*o4], sb[4*o4+1], sb[4*o4+2], sb[4*o4+3]);

  for (int ci = 0; ci < 64; ci++) {
    float v = xb[(size_t)ci << 14];
    const float4* wr = (const float4*)&sw[ci * 64];
    #pragma unroll
    for (int o4 = 0; o4 < 16; o4++) {
      float4 w4 = wr[o4];
      acc[o4].x += w4.x * v; acc[o4].y += w4.y * v;
      acc[o4].z += w4.z * v; acc[o4].w += w4.w * v;
    }
  }
  for (int ci = 0; ci < 64; ci++) {
    float v = rb[(size_t)ci << 14];
    const float4* wr = (const float4*)&sw[(64 + ci) * 64];
    #pragma unroll
    for (int o4 = 0; o4 < 16; o4++) {
      float4 w4 = wr[o4];
      acc[o4].x += w4.x * v; acc[o4].y += w4.y * v;
      acc[o4].z += w4.z * v; acc[o4].w += w4.w * v;
    }
  }
  ushort* fb = fusedb + ((size_t)b * 64 << 14) + hw;
  #pragma unroll
  for (int o4 = 0; o4 < 16; o4++) {
    fb[(size_t)(4*o4+0) << 14] = f2bf(acc[o4].x);
    fb[(size_t)(4*o4+1) << 14] = f2bf(acc[o4].y);
    fb[(size_t)(4*o4+2) << 14] = f2bf(acc[o4].z);
    fb[(size_t)(4*o4+3) << 14] = f2bf(acc[o4].w);
  }
}

// ---- K2: xt[b][hw][c] fp32 pixel-major transpose of x --------------------------------
__global__ __launch_bounds__(256) void k_xt(
    const float* __restrict__ x, float* __restrict__ xt) {
  __shared__ float sx[64][65];
  const int t = threadIdx.x;
  const int b = blockIdx.x >> 8, hw0 = (blockIdx.x & 255) << 6;
  for (int i = t; i < 4096; i += 256) {
    int c = i >> 6, hwi = i & 63;
    sx[c][hwi] = x[((size_t)(b * 64 + c) << 14) + hw0 + hwi];
  }
  __syncthreads();
  for (int i = t; i < 4096; i += 256) {
    int hwi = i >> 6, c = i & 63;
    xt[(((size_t)b << 14) + hw0 + hwi) * 64 + c] = sx[c][hwi];
  }
}

// ---- K3: im2col A[m=65536][k=576] bf16 (k = ci*9 + kk) --------------------------------
__global__ __launch_bounds__(256) void k_im2col(
    const ushort* __restrict__ fusedb, ushort* __restrict__ A) {
  __shared__ ushort sF[64 * 432];   // [ci][dr 3][144], row data at col offset 8
  const int t = threadIdx.x;
  const int bh = blockIdx.x;        // (b,h)
  const int b = bh >> 7, h = bh & 127;

  for (int idx = t; idx < 3072; idx += 256) {
    int ci = idx / 48, rem = idx - ci * 48, dr = rem >> 4, w8 = rem & 15;
    int gh = h + dr - 1;
    uint4 v = make_uint4(0u, 0u, 0u, 0u);
    if (gh >= 0 && gh < 128)
      v = *(const uint4*)(fusedb + (((size_t)(b * 64 + ci)) << 14) + (gh << 7) + w8 * 8);
    *(uint4*)(&sF[ci * 432 + dr * 144 + 8 + w8 * 8]) = v;
  }
  for (int idx = t; idx < 192; idx += 256) {
    int ci = idx / 3, dr = idx - ci * 3;
    sF[ci * 432 + dr * 144 + 7]   = 0;
    sF[ci * 432 + dr * 144 + 136] = 0;
  }
  __syncthreads();

  const size_t mbase = (size_t)bh * 128;
  #pragma unroll 1
  for (int it = 0; it < 36; it++) {
    int idx = it * 256 + t;
    int kg8 = idx & 7, w8i = (idx >> 3) & 7;
    int rest = idx >> 6;
    int kghi = rest % 9, whi = rest / 9;
    int kg = kghi * 8 + kg8;
    int w  = whi * 8 + w8i;
    ushort vals[8];
    #pragma unroll
    for (int j = 0; j < 8; j++) {
      int kgl = kg * 8 + j;
      int ci = kgl / 9, kk = kgl - ci * 9;
      int dr = kk / 3, dc = kk - dr * 3;
      vals[j] = sF[ci * 432 + dr * 144 + w + dc + 7];
    }
    *(uint4*)(A + (mbase + w) * 576 + kg * 8) = *(uint4*)vals;
  }
}

// ---- K4: MFMA GEMM head[640][pix] = Wb x A^T, fused bias+act --------------------------
// grid (pt 512, og 5); block 256 = 4 waves; tile 128 oc x 128 px; wave = 64oc x 64px.
__global__ __launch_bounds__(256) void k_gemm(
    const ushort* __restrict__ Wb, const ushort* __restrict__ A,
    const float* __restrict__ Bc,
    float* __restrict__ headom, ushort* __restrict__ headcol) {
  __shared__ __align__(16) ushort sW[128 * 32];
  __shared__ __align__(16) ushort sP[128 * 32];
  const int t = threadIdx.x;
  const int lane = t & 63, wv = t >> 6;
  const int og = blockIdx.y;              // 0..4
  const int m0 = blockIdx.x * 128;        // pixel base
  const int bb = m0 >> 14, hw0 = m0 & 16383;
  const ushort* Wrow = Wb + (size_t)(og * 128) * 576;

  f32x4 acc[4][4];
  #pragma unroll
  for (int mi = 0; mi < 4; mi++)
    #pragma unroll
    for (int ni = 0; ni < 4; ni++) acc[mi][ni] = (f32x4){0.f, 0.f, 0.f, 0.f};

  const int srow = lane >> 2, sslot = lane & 3;
  const int ocq = wv & 1, pxq = wv >> 1;

  for (int ks = 0; ks < 18; ks++) {
    const int k0 = ks * 32;
    __syncthreads();
    #pragma unroll
    for (int c = 0; c < 2; c++) {
      int row = (wv << 5) + (c << 4) + srow;      // 0..127
      int g = (sslot - (row >> 1)) & 3;
      gload_lds16(Wrow + (size_t)row * 576 + k0 + g * 8,
                  sW + (((wv << 5) + (c << 4)) << 5));
      gload_lds16(A + (size_t)(m0 + row) * 576 + k0 + g * 8,
                  sP + (((wv << 5) + (c << 4)) << 5));
    }
    __syncthreads();

    const int nif = lane & 15, kb = lane >> 4;
    s16x8 af[4], bfr[4];
    #pragma unroll
    for (int mi = 0; mi < 4; mi++) {
      int m = (ocq << 6) + mi * 16 + nif;
      int s = (kb + (m >> 1)) & 3;
      af[mi] = *(const s16x8*)(sW + m * 32 + s * 8);
    }
    #pragma unroll
    for (int ni = 0; ni < 4; ni++) {
      int r = (pxq << 6) + ni * 16 + nif;
      int s = (kb + (r >> 1)) & 3;
      bfr[ni] = *(const s16x8*)(sP + r * 32 + s * 8);
    }
    #pragma unroll
    for (int mi = 0; mi < 4; mi++)
      #pragma unroll
      for (int ni = 0; ni < 4; ni++)
        acc[mi][ni] = __builtin_amdgcn_mfma_f32_16x16x32_bf16(af[mi], bfr[ni], acc[mi][ni], 0, 0, 0);
  }

  const int nif = lane & 15, quad = lane >> 4;
  #pragma unroll
  for (int mi = 0; mi < 4; mi++) {
    #pragma unroll
    for (int ni = 0; ni < 4; ni++) {
      int hw = hw0 + (pxq << 6) + ni * 16 + nif;
      #pragma unroll
      for (int r = 0; r < 4; r++) {
        int g = og * 128 + (ocq << 6) + mi * 16 + quad * 4 + r;
        float v = acc[mi][ni][r] + Bc[g];
        if (g < 18) {
          headom[(((size_t)bb * 27 + g) << 14) + hw] = v;
        } else if (g < 27) {
          headom[(((size_t)bb * 27 + g) << 14) + hw] = 1.f / (1.f + expf(-v));
        } else if (g < 603) {
          headcol[(((size_t)bb * 576 + (g - 27)) << 14) + hw] = f2bf(tanhf(v));
        }
      }
    }
  }
}

// ---- K5: sampler -> inp bf16 U[pix][576] (ck = c*9 + k), reuses A's buffer ------------
// thread = (pixel, channel-quarter): wave = one cq, 64 consecutive pixels.
__global__ __launch_bounds__(256) void k_samp(
    const float* __restrict__ xt, const float* __restrict__ headom,
    const ushort* __restrict__ headcol, ushort* __restrict__ U) {
  const int t = threadIdx.x;
  const int cq = t >> 6;
  const int pix = blockIdx.x * 64 + (t & 63);
  const int b = pix >> 14, hw = pix & 16383;
  const int h = hw >> 7, w = hw & 127;
  const float* hbom = headom + (((size_t)b * 27) << 14) + hw;

  float wl[9][4];
  int   ofs[9][4];
  float mk[9];
  #pragma unroll
  for (int k = 0; k < 9; k++) {
    float ox = hbom[(size_t)k << 14];
    float oy = hbom[(size_t)(9 + k) << 14];
    mk[k]    = hbom[(size_t)(18 + k) << 14];
    float px = (float)(h + k / 3) + ox;
    float py = (float)(w + k % 3) + oy;
    float fx = floorf(px), fy = floorf(py);
    float qltx = fminf(fmaxf(fx, 0.f), 129.f);
    float qlty = fminf(fmaxf(fy, 0.f), 129.f);
    float qrbx = fminf(fmaxf(fx + 1.f, 0.f), 129.f);
    float qrby = fminf(fmaxf(fy + 1.f, 0.f), 129.f);
    float sx = fminf(fmaxf(px, 0.f), 129.f);
    float sy = fminf(fmaxf(py, 0.f), 129.f);
    float ax = 1.f + qltx - sx, bx = 1.f - qrbx + sx;
    float ay = 1.f + qlty - sy, by = 1.f - qrby + sy;
    int iltx = (int)qltx, ilty = (int)qlty, irbx = (int)qrbx, irby = (int)qrby;
    bool vltx = (iltx >= 1) && (iltx <= 128);
    bool vlty = (ilty >= 1) && (ilty <= 128);
    bool vrbx = (irbx >= 1) && (irbx <= 128);
    bool vrby = (irby >= 1) && (irby <= 128);
    wl[k][0] = (vltx && vlty) ? ax * ay : 0.f;
    wl[k][1] = (vrbx && vrby) ? bx * by : 0.f;
    wl[k][2] = (vltx && vrby) ? ax * by : 0.f;
    wl[k][3] = (vrbx && vlty) ? bx * ay : 0.f;
    ofs[k][0] = (vltx && vlty) ? ((iltx - 1) << 7) + (ilty - 1) : 0;
    ofs[k][1] = (vrbx && vrby) ? ((irbx - 1) << 7) + (irby - 1) : 0;
    ofs[k][2] = (vltx && vrby) ? ((iltx - 1) << 7) + (irby - 1) : 0;
    ofs[k][3] = (vrbx && vlty) ? ((irbx - 1) << 7) + (ilty - 1) : 0;
  }

  const float* xb = xt + (((size_t)b << 14) << 6);   // xt[b][hw][64]
  const ushort* colb = headcol + (((size_t)b * 576) << 14) + hw;

  #pragma unroll 1
  for (int half = 0; half < 2; half++) {
    const int c0 = cq * 16 + half * 8;
    ushort vals[72];
    #pragma unroll
    for (int k = 0; k < 9; k++) {
      float pos[8] = {0.f, 0.f, 0.f, 0.f, 0.f, 0.f, 0.f, 0.f};
      #pragma unroll
      for (int corner = 0; corner < 4; corner++) {
        const float* p = xb + ((size_t)ofs[k][corner] << 6) + c0;
        float4 v0 = *(const float4*)p;
        float4 v1 = *(const float4*)(p + 4);
        float wgt = wl[k][corner];
        pos[0] += wgt * v0.x; pos[1] += wgt * v0.y;
        pos[2] += wgt * v0.z; pos[3] += wgt * v0.w;
        pos[4] += wgt * v1.x; pos[5] += wgt * v1.y;
        pos[6] += wgt * v1.z; pos[7] += wgt * v1.w;
      }
      #pragma unroll
      for (int j = 0; j < 8; j++) {
        float col = bf2f(colb[(size_t)((c0 + j) * 9 + k) << 14]);
        vals[j * 9 + k] = f2bf((col + pos[j]) * mk[k]);
      }
    }
    ushort* up = U + (size_t)pix * 576 + c0 * 9;
    #pragma unroll
    for (int j = 0; j < 9; j++)
      *(uint4*)(up + j * 8) = *(uint4*)(vals + j * 8);
  }
}

// ---- K6: MFMA GEMM out[64][pix] = Wb2 x U^T -------------------------------------------
__global__ __launch_bounds__(256) void k_out(
    const ushort* __restrict__ W2, const ushort* __restrict__ U,
    float* __restrict__ out) {
  __shared__ __align__(16) ushort sW[64 * 32];
  __shared__ __align__(16) ushort sP[256 * 32];
  const int t = threadIdx.x;
  const int lane = t & 63, wv = t >> 6;
  const int m0 = blockIdx.x * 256;
  const int bb = m0 >> 14, hw0 = m0 & 16383;

  f32x4 acc[4][4];
  #pragma unroll
  for (int mi = 0; mi < 4; mi++)
    #pragma unroll
    for (int ni = 0; ni < 4; ni++) acc[mi][ni] = (f32x4){0.f, 0.f, 0.f, 0.f};

  const int srow = lane >> 2, sslot = lane & 3;

  for (int ks = 0; ks < 18; ks++) {
    const int k0 = ks * 32;
    __syncthreads();
    {
      int row = (wv << 4) + srow;
      int g = (sslot - (row >> 1)) & 3;
      gload_lds16(W2 + (size_t)row * 576 + k0 + g * 8, sW + (wv << 9));
    }
    #pragma unroll
    for (int c = 0; c < 4; c++) {
      int prow = (wv << 6) + (c << 4) + srow;
      int g = (sslot - (prow >> 1)) & 3;
      gload_lds16(U + (size_t)(m0 + prow) * 576 + k0 + g * 8,
                  sP + (((wv << 6) + (c << 4)) << 5));
    }
    __syncthreads();

    const int nif = lane & 15, kb = lane >> 4;
    s16x8 af[4], bfr[4];
    #pragma unroll
    for (int mi = 0; mi < 4; mi++) {
      int m = mi * 16 + nif;
      int s = (kb + (m >> 1)) & 3;
      af[mi] = *(const s16x8*)(sW + m * 32 + s * 8);
    }
    #pragma unroll
    for (int ni = 0; ni < 4; ni++) {
      int r = (wv << 6) + ni * 16 + nif;
      int s = (kb + (r >> 1)) & 3;
      bfr[ni] = *(const s16x8*)(sP + r * 32 + s * 8);
    }
    #pragma unroll
    for (int mi = 0; mi < 4; mi++)
      #pragma unroll
      for (int ni = 0; ni < 4; ni++)
        acc[mi][ni] = __builtin_amdgcn_mfma_f32_16x16x32_bf16(af[mi], bfr[ni], acc[mi][ni], 0, 0, 0);
  }

  const int nif = lane & 15, quad = lane >> 4;
  #pragma unroll
  for (int mi = 0; mi < 4; mi++) {
    #pragma unroll
    for (int ni = 0; ni < 4; ni++) {
      int hw = hw0 + (wv << 6) + ni * 16 + nif;
      #pragma unroll
      for (int r = 0; r < 4; r++) {
        int g = mi * 16 + quad * 4 + r;
        out[(((size_t)bb * 64 + g) << 14) + hw] = acc[mi][ni][r];
      }
    }
  }
}

extern "C" void kernel_launch(void* const* d_in, const int* in_sizes, int n_in,
                              void* d_out, int out_size, void* d_ws, size_t ws_size,
                              hipStream_t stream) {
  const float* x     = (const float*)d_in[0];
  const float* ref   = (const float*)d_in[1];
  const float* wcd   = (const float*)d_in[2];
  const float* bcd   = (const float*)d_in[3];
  const float* wp    = (const float*)d_in[4];
  const float* bp    = (const float*)d_in[5];
  const float* wm    = (const float*)d_in[6];
  const float* bm    = (const float*)d_in[7];
  const float* wc    = (const float*)d_in[8];
  const float* bc    = (const float*)d_in[9];
  const float* wconv = (const float*)d_in[10];
  float* out = (float*)d_out;

  char* w8 = (char*)d_ws;
  ushort* Wb      = (ushort*)(w8 + 0);           //    737,280 B
  float*  Bc      = (float*)(w8 + 737280);       //      2,560 B
  ushort* Wb2     = (ushort*)(w8 + 739840);      //     73,728 B
  ushort* fusedb  = (ushort*)(w8 + 813568);      //  8,388,608 B
  ushort* A       = (ushort*)(w8 + 9202176);     // 75,497,472 B (also U after k_gemm)
  float*  headom  = (float*)(w8 + 84699648);     //  7,077,888 B
  ushort* headcol = (ushort*)(w8 + 91777536);    // 75,497,472 B
  float*  xt      = (float*)(w8 + 167275008);    // 16,777,216 B -> total 184,052,224 B
  ushort* U       = A;  // inp reuses A's buffer (A fully consumed by k_gemm first)

  k_merge <<<1440, 256, 0, stream>>>(wp, bp, wm, bm, wc, bc, wconv, Wb, Bc, Wb2);
  k_fused <<<256, 256, 0, stream>>>(x, ref, wcd, bcd, fusedb);
  k_xt    <<<1024, 256, 0, stream>>>(x, xt);
  k_im2col<<<512, 256, 0, stream>>>(fusedb, A);
  k_gemm  <<<dim3(512, 5), 256, 0, stream>>>(Wb, A, Bc, headom, headcol);
  k_samp  <<<1024, 256, 0, stream>>>(xt, headom, headcol, U);
  k_out   <<<256, 256, 0, stream>>>(Wb2, U, out);
}

// Round 5
// 451.475 us; speedup vs baseline: 2.2023x; 1.0138x over previous
//
#include <hip/hip_runtime.h>
#include <math.h>

typedef short s16x8 __attribute__((ext_vector_type(8)));
typedef float f32x4 __attribute__((ext_vector_type(4)));

__device__ inline ushort f2bf(float f) {
  unsigned u = __float_as_uint(f);
  u = (u + 0x7FFF + ((u >> 16) & 1)) >> 16;
  return (ushort)u;
}
__device__ inline float bf2f(ushort u) {
  return __uint_as_float(((unsigned)u) << 16);
}
__device__ inline void gload_lds16(const void* g, void* l) {
  __builtin_amdgcn_global_load_lds(
      (const __attribute__((address_space(1))) unsigned*)g,
      (__attribute__((address_space(3))) unsigned*)l, 16, 0, 0);
}

// ---- K0: Wb bf16[640][576] + Bc[640] + Wb2 bf16[64][576] (K-PERMUTED: k*64+c) ---------
__global__ __launch_bounds__(256) void k_merge(
    const float* __restrict__ wp, const float* __restrict__ bp,
    const float* __restrict__ wm, const float* __restrict__ bm,
    const float* __restrict__ wc, const float* __restrict__ bc,
    const float* __restrict__ wconv,
    ushort* __restrict__ Wb, float* __restrict__ Bc, ushort* __restrict__ Wb2) {
  int i = blockIdx.x * 256 + threadIdx.x;
  if (i < 640 * 576) {
    int g = i / 576, r = i - g * 576;
    float v = 0.f;
    if (g < 18)       v = wp[g * 576 + r];
    else if (g < 27)  v = wm[(g - 18) * 576 + r];
    else if (g < 603) v = wc[(g - 27) * 576 + r];
    Wb[i] = f2bf(v);
  }
  if (i < 64 * 576) {             // Wb2[o][k*64+c] = wconv[o][c*9+k]
    int o = i / 576, r = i - o * 576;
    int kk = r >> 6, c = r & 63;
    Wb2[i] = f2bf(wconv[o * 576 + c * 9 + kk]);
  }
  if (i < 640)
    Bc[i] = (i < 18) ? bp[i] : (i < 27) ? bm[i - 18] : (i < 603) ? bc[i - 27] : 0.f;
}

// ---- K1: fused = 1x1 conv over concat(x, ref), output bf16 [64][B*HW] -----------------
__global__ __launch_bounds__(256) void k_fused(
    const float* __restrict__ x, const float* __restrict__ ref,
    const float* __restrict__ wcd, const float* __restrict__ bcd,
    ushort* __restrict__ fusedb) {
  __shared__ float sw[128 * 64];
  __shared__ float sb[64];
  for (int i = threadIdx.x; i < 128 * 64; i += 256) {
    int ci = i >> 6, o = i & 63;
    sw[i] = wcd[o * 128 + ci];
  }
  if (threadIdx.x < 64) sb[threadIdx.x] = bcd[threadIdx.x];
  __syncthreads();

  int pix = blockIdx.x * 256 + threadIdx.x;
  int b = pix >> 14, hw = pix & 16383;
  const float* xb = x   + ((size_t)b * 64 << 14) + hw;
  const float* rb = ref + ((size_t)b * 64 << 14) + hw;

  float4 acc[16];
  #pragma unroll
  for (int o4 = 0; o4 < 16; o4++)
    acc[o4] = make_float4(sb[4*o4], sb[4*o4+1], sb[4*o4+2], sb[4*o4+3]);

  for (int ci = 0; ci < 64; ci++) {
    float v = xb[(size_t)ci << 14];
    const float4* wr = (const float4*)&sw[ci * 64];
    #pragma unroll
    for (int o4 = 0; o4 < 16; o4++) {
      float4 w4 = wr[o4];
      acc[o4].x += w4.x * v; acc[o4].y += w4.y * v;
      acc[o4].z += w4.z * v; acc[o4].w += w4.w * v;
    }
  }
  for (int ci = 0; ci < 64; ci++) {
    float v = rb[(size_t)ci << 14];
    const float4* wr = (const float4*)&sw[(64 + ci) * 64];
    #pragma unroll
    for (int o4 = 0; o4 < 16; o4++) {
      float4 w4 = wr[o4];
      acc[o4].x += w4.x * v; acc[o4].y += w4.y * v;
      acc[o4].z += w4.z * v; acc[o4].w += w4.w * v;
    }
  }
  ushort* fb = fusedb + ((size_t)b * 64 << 14) + hw;
  #pragma unroll
  for (int o4 = 0; o4 < 16; o4++) {
    fb[(size_t)(4*o4+0) << 14] = f2bf(acc[o4].x);
    fb[(size_t)(4*o4+1) << 14] = f2bf(acc[o4].y);
    fb[(size_t)(4*o4+2) << 14] = f2bf(acc[o4].z);
    fb[(size_t)(4*o4+3) << 14] = f2bf(acc[o4].w);
  }
}

// ---- K2: xt[b][hw][c] fp32 pixel-major transpose of x --------------------------------
__global__ __launch_bounds__(256) void k_xt(
    const float* __restrict__ x, float* __restrict__ xt) {
  __shared__ float sx[64][65];
  const int t = threadIdx.x;
  const int b = blockIdx.x >> 8, hw0 = (blockIdx.x & 255) << 6;
  for (int i = t; i < 4096; i += 256) {
    int c = i >> 6, hwi = i & 63;
    sx[c][hwi] = x[((size_t)(b * 64 + c) << 14) + hw0 + hwi];
  }
  __syncthreads();
  for (int i = t; i < 4096; i += 256) {
    int hwi = i >> 6, c = i & 63;
    xt[(((size_t)b << 14) + hw0 + hwi) * 64 + c] = sx[c][hwi];
  }
}

// ---- K3: im2col A[m=65536][k=576] bf16 (k = ci*9 + kk) --------------------------------
__global__ __launch_bounds__(256) void k_im2col(
    const ushort* __restrict__ fusedb, ushort* __restrict__ A) {
  __shared__ ushort sF[64 * 432];   // [ci][dr 3][144], row data at col offset 8
  const int t = threadIdx.x;
  const int bh = blockIdx.x;        // (b,h)
  const int b = bh >> 7, h = bh & 127;

  for (int idx = t; idx < 3072; idx += 256) {
    int ci = idx / 48, rem = idx - ci * 48, dr = rem >> 4, w8 = rem & 15;
    int gh = h + dr - 1;
    uint4 v = make_uint4(0u, 0u, 0u, 0u);
    if (gh >= 0 && gh < 128)
      v = *(const uint4*)(fusedb + (((size_t)(b * 64 + ci)) << 14) + (gh << 7) + w8 * 8);
    *(uint4*)(&sF[ci * 432 + dr * 144 + 8 + w8 * 8]) = v;
  }
  for (int idx = t; idx < 192; idx += 256) {
    int ci = idx / 3, dr = idx - ci * 3;
    sF[ci * 432 + dr * 144 + 7]   = 0;
    sF[ci * 432 + dr * 144 + 136] = 0;
  }
  __syncthreads();

  const size_t mbase = (size_t)bh * 128;
  #pragma unroll 1
  for (int it = 0; it < 36; it++) {
    int idx = it * 256 + t;
    int kg8 = idx & 7, w8i = (idx >> 3) & 7;
    int rest = idx >> 6;
    int kghi = rest % 9, whi = rest / 9;
    int kg = kghi * 8 + kg8;
    int w  = whi * 8 + w8i;
    ushort vals[8];
    #pragma unroll
    for (int j = 0; j < 8; j++) {
      int kgl = kg * 8 + j;
      int ci = kgl / 9, kk = kgl - ci * 9;
      int dr = kk / 3, dc = kk - dr * 3;
      vals[j] = sF[ci * 432 + dr * 144 + w + dc + 7];
    }
    *(uint4*)(A + (mbase + w) * 576 + kg * 8) = *(uint4*)vals;
  }
}

// ---- K4: MFMA GEMM head[640][pix] = Wb x A^T, fused bias+act --------------------------
// grid (og 5, pt 512): og fast dim -> 5 blocks sharing one A-tile dispatch together.
__global__ __launch_bounds__(256) void k_gemm(
    const ushort* __restrict__ Wb, const ushort* __restrict__ A,
    const float* __restrict__ Bc,
    float* __restrict__ headom, ushort* __restrict__ headcol) {
  __shared__ __align__(16) ushort sW[128 * 32];
  __shared__ __align__(16) ushort sP[128 * 32];
  const int t = threadIdx.x;
  const int lane = t & 63, wv = t >> 6;
  const int og = blockIdx.x;              // 0..4
  const int m0 = blockIdx.y * 128;        // pixel base
  const int bb = m0 >> 14, hw0 = m0 & 16383;
  const ushort* Wrow = Wb + (size_t)(og * 128) * 576;

  f32x4 acc[4][4];
  #pragma unroll
  for (int mi = 0; mi < 4; mi++)
    #pragma unroll
    for (int ni = 0; ni < 4; ni++) acc[mi][ni] = (f32x4){0.f, 0.f, 0.f, 0.f};

  const int srow = lane >> 2, sslot = lane & 3;
  const int ocq = wv & 1, pxq = wv >> 1;

  for (int ks = 0; ks < 18; ks++) {
    const int k0 = ks * 32;
    __syncthreads();
    #pragma unroll
    for (int c = 0; c < 2; c++) {
      int row = (wv << 5) + (c << 4) + srow;      // 0..127
      int g = (sslot - (row >> 1)) & 3;
      gload_lds16(Wrow + (size_t)row * 576 + k0 + g * 8,
                  sW + (((wv << 5) + (c << 4)) << 5));
      gload_lds16(A + (size_t)(m0 + row) * 576 + k0 + g * 8,
                  sP + (((wv << 5) + (c << 4)) << 5));
    }
    __syncthreads();

    const int nif = lane & 15, kb = lane >> 4;
    s16x8 af[4], bfr[4];
    #pragma unroll
    for (int mi = 0; mi < 4; mi++) {
      int m = (ocq << 6) + mi * 16 + nif;
      int s = (kb + (m >> 1)) & 3;
      af[mi] = *(const s16x8*)(sW + m * 32 + s * 8);
    }
    #pragma unroll
    for (int ni = 0; ni < 4; ni++) {
      int r = (pxq << 6) + ni * 16 + nif;
      int s = (kb + (r >> 1)) & 3;
      bfr[ni] = *(const s16x8*)(sP + r * 32 + s * 8);
    }
    #pragma unroll
    for (int mi = 0; mi < 4; mi++)
      #pragma unroll
      for (int ni = 0; ni < 4; ni++)
        acc[mi][ni] = __builtin_amdgcn_mfma_f32_16x16x32_bf16(af[mi], bfr[ni], acc[mi][ni], 0, 0, 0);
  }

  const int nif = lane & 15, quad = lane >> 4;
  #pragma unroll
  for (int mi = 0; mi < 4; mi++) {
    #pragma unroll
    for (int ni = 0; ni < 4; ni++) {
      int hw = hw0 + (pxq << 6) + ni * 16 + nif;
      #pragma unroll
      for (int r = 0; r < 4; r++) {
        int g = og * 128 + (ocq << 6) + mi * 16 + quad * 4 + r;
        float v = acc[mi][ni][r] + Bc[g];
        if (g < 18) {
          headom[(((size_t)bb * 27 + g) << 14) + hw] = v;
        } else if (g < 27) {
          headom[(((size_t)bb * 27 + g) << 14) + hw] = 1.f / (1.f + expf(-v));
        } else if (g < 603) {
          headcol[(((size_t)bb * 576 + (g - 27)) << 14) + hw] = f2bf(tanhf(v));
        }
      }
    }
  }
}

// ---- K5: sampler -> inp bf16 U[pix][576] K-PERMUTED: index k*64+c ---------------------
// k-outer loop keeps VGPR low; thread = (pixel, channel-quarter 16ch).
__global__ __launch_bounds__(256, 4) void k_samp(
    const float* __restrict__ xt, const float* __restrict__ headom,
    const ushort* __restrict__ headcol, ushort* __restrict__ U) {
  const int t = threadIdx.x;
  const int cq = t >> 6;                      // 0..3 -> channels cq*16 .. +16
  const int pix = blockIdx.x * 64 + (t & 63);
  const int b = pix >> 14, hw = pix & 16383;
  const int h = hw >> 7, w = hw & 127;
  const float* hbom = headom + (((size_t)b * 27) << 14) + hw;
  const float* xb = xt + ((size_t)b << 20);   // xt[b][hw][64]
  const ushort* colb = headcol + (((size_t)b * 576) << 14) + hw;
  ushort* up = U + (size_t)pix * 576 + cq * 16;

  #pragma unroll 1
  for (int k = 0; k < 9; k++) {
    float ox = hbom[(size_t)k << 14];
    float oy = hbom[(size_t)(9 + k) << 14];
    float mk = hbom[(size_t)(18 + k) << 14];
    float px = (float)(h + k / 3) + ox;
    float py = (float)(w + k % 3) + oy;
    float fx = floorf(px), fy = floorf(py);
    float qltx = fminf(fmaxf(fx, 0.f), 129.f);
    float qlty = fminf(fmaxf(fy, 0.f), 129.f);
    float qrbx = fminf(fmaxf(fx + 1.f, 0.f), 129.f);
    float qrby = fminf(fmaxf(fy + 1.f, 0.f), 129.f);
    float sx = fminf(fmaxf(px, 0.f), 129.f);
    float sy = fminf(fmaxf(py, 0.f), 129.f);
    float ax = 1.f + qltx - sx, bx = 1.f - qrbx + sx;
    float ay = 1.f + qlty - sy, by = 1.f - qrby + sy;
    int iltx = (int)qltx, ilty = (int)qlty, irbx = (int)qrbx, irby = (int)qrby;
    bool vltx = (iltx >= 1) && (iltx <= 128);
    bool vlty = (ilty >= 1) && (ilty <= 128);
    bool vrbx = (irbx >= 1) && (irbx <= 128);
    bool vrby = (irby >= 1) && (irby <= 128);
    float wl[4];
    int   ofs[4];
    wl[0] = (vltx && vlty) ? ax * ay : 0.f;
    wl[1] = (vrbx && vrby) ? bx * by : 0.f;
    wl[2] = (vltx && vrby) ? ax * by : 0.f;
    wl[3] = (vrbx && vlty) ? bx * ay : 0.f;
    ofs[0] = (vltx && vlty) ? ((iltx - 1) << 7) + (ilty - 1) : 0;
    ofs[1] = (vrbx && vrby) ? ((irbx - 1) << 7) + (irby - 1) : 0;
    ofs[2] = (vltx && vrby) ? ((iltx - 1) << 7) + (irby - 1) : 0;
    ofs[3] = (vrbx && vlty) ? ((irbx - 1) << 7) + (ilty - 1) : 0;

    float pos[16];
    #pragma unroll
    for (int j = 0; j < 16; j++) pos[j] = 0.f;
    #pragma unroll
    for (int corner = 0; corner < 4; corner++) {
      const float* p = xb + ((size_t)ofs[corner] << 6) + cq * 16;
      float wgt = wl[corner];
      #pragma unroll
      for (int q = 0; q < 4; q++) {
        float4 v = *(const float4*)(p + 4 * q);
        pos[4*q+0] += wgt * v.x; pos[4*q+1] += wgt * v.y;
        pos[4*q+2] += wgt * v.z; pos[4*q+3] += wgt * v.w;
      }
    }
    ushort vals[16];
    #pragma unroll
    for (int j = 0; j < 16; j++) {
      float col = bf2f(colb[(size_t)((cq * 16 + j) * 9 + k) << 14]);
      vals[j] = f2bf((col + pos[j]) * mk);
    }
    *(uint4*)(up + k * 64)     = *(uint4*)(vals);
    *(uint4*)(up + k * 64 + 8) = *(uint4*)(vals + 8);
  }
}

// ---- K6: MFMA GEMM out[64][pix] = Wb2 x U^T (both K-permuted consistently) ------------
__global__ __launch_bounds__(256) void k_out(
    const ushort* __restrict__ W2, const ushort* __restrict__ U,
    float* __restrict__ out) {
  __shared__ __align__(16) ushort sW[64 * 32];
  __shared__ __align__(16) ushort sP[256 * 32];
  const int t = threadIdx.x;
  const int lane = t & 63, wv = t >> 6;
  const int m0 = blockIdx.x * 256;
  const int bb = m0 >> 14, hw0 = m0 & 16383;

  f32x4 acc[4][4];
  #pragma unroll
  for (int mi = 0; mi < 4; mi++)
    #pragma unroll
    for (int ni = 0; ni < 4; ni++) acc[mi][ni] = (f32x4){0.f, 0.f, 0.f, 0.f};

  const int srow = lane >> 2, sslot = lane & 3;

  for (int ks = 0; ks < 18; ks++) {
    const int k0 = ks * 32;
    __syncthreads();
    {
      int row = (wv << 4) + srow;
      int g = (sslot - (row >> 1)) & 3;
      gload_lds16(W2 + (size_t)row * 576 + k0 + g * 8, sW + (wv << 9));
    }
    #pragma unroll
    for (int c = 0; c < 4; c++) {
      int prow = (wv << 6) + (c << 4) + srow;
      int g = (sslot - (prow >> 1)) & 3;
      gload_lds16(U + (size_t)(m0 + prow) * 576 + k0 + g * 8,
                  sP + (((wv << 6) + (c << 4)) << 5));
    }
    __syncthreads();

    const int nif = lane & 15, kb = lane >> 4;
    s16x8 af[4], bfr[4];
    #pragma unroll
    for (int mi = 0; mi < 4; mi++) {
      int m = mi * 16 + nif;
      int s = (kb + (m >> 1)) & 3;
      af[mi] = *(const s16x8*)(sW + m * 32 + s * 8);
    }
    #pragma unroll
    for (int ni = 0; ni < 4; ni++) {
      int r = (wv << 6) + ni * 16 + nif;
      int s = (kb + (r >> 1)) & 3;
      bfr[ni] = *(const s16x8*)(sP + r * 32 + s * 8);
    }
    #pragma unroll
    for (int mi = 0; mi < 4; mi++)
      #pragma unroll
      for (int ni = 0; ni < 4; ni++)
        acc[mi][ni] = __builtin_amdgcn_mfma_f32_16x16x32_bf16(af[mi], bfr[ni], acc[mi][ni], 0, 0, 0);
  }

  const int nif = lane & 15, quad = lane >> 4;
  #pragma unroll
  for (int mi = 0; mi < 4; mi++) {
    #pragma unroll
    for (int ni = 0; ni < 4; ni++) {
      int hw = hw0 + (wv << 6) + ni * 16 + nif;
      #pragma unroll
      for (int r = 0; r < 4; r++) {
        int g = mi * 16 + quad * 4 + r;
        out[(((size_t)bb * 64 + g) << 14) + hw] = acc[mi][ni][r];
      }
    }
  }
}

extern "C" void kernel_launch(void* const* d_in, const int* in_sizes, int n_in,
                              void* d_out, int out_size, void* d_ws, size_t ws_size,
                              hipStream_t stream) {
  const float* x     = (const float*)d_in[0];
  const float* ref   = (const float*)d_in[1];
  const float* wcd   = (const float*)d_in[2];
  const float* bcd   = (const float*)d_in[3];
  const float* wp    = (const float*)d_in[4];
  const float* bp    = (const float*)d_in[5];
  const float* wm    = (const float*)d_in[6];
  const float* bm    = (const float*)d_in[7];
  const float* wc    = (const float*)d_in[8];
  const float* bc    = (const float*)d_in[9];
  const float* wconv = (const float*)d_in[10];
  float* out = (float*)d_out;

  char* w8 = (char*)d_ws;
  ushort* Wb      = (ushort*)(w8 + 0);           //    737,280 B
  float*  Bc      = (float*)(w8 + 737280);       //      2,560 B
  ushort* Wb2     = (ushort*)(w8 + 739840);      //     73,728 B
  ushort* fusedb  = (ushort*)(w8 + 813568);      //  8,388,608 B
  ushort* A       = (ushort*)(w8 + 9202176);     // 75,497,472 B (also U after k_gemm)
  float*  headom  = (float*)(w8 + 84699648);     //  7,077,888 B
  ushort* headcol = (ushort*)(w8 + 91777536);    // 75,497,472 B
  float*  xt      = (float*)(w8 + 167275008);    // 16,777,216 B -> total 184,052,224 B
  ushort* U       = A;  // inp reuses A's buffer (A fully consumed by k_gemm first)

  k_merge <<<1440, 256, 0, stream>>>(wp, bp, wm, bm, wc, bc, wconv, Wb, Bc, Wb2);
  k_fused <<<256, 256, 0, stream>>>(x, ref, wcd, bcd, fusedb);
  k_xt    <<<1024, 256, 0, stream>>>(x, xt);
  k_im2col<<<512, 256, 0, stream>>>(fusedb, A);
  k_gemm  <<<dim3(5, 512), 256, 0, stream>>>(Wb, A, Bc, headom, headcol);
  k_samp  <<<1024, 256, 0, stream>>>(xt, headom, headcol, U);
  k_out   <<<256, 256, 0, stream>>>(Wb2, U, out);
}